// Round 1
// baseline (662.434 us; speedup 1.0000x reference)
//
#include <hip/hip_runtime.h>
#include <math.h>

#define BDIM 8
#define CDIM 256
#define C4DIM 64
#define NDIM 2048

// ---------------------------------------------------------------------------
// GEMM: OUT = W (M x 256) * X[b] (256 x N)  (+bias)
// TRANS_OUT: write OUT[b][n][o] (row length 64, used for qT); else OUT[b][o][n].
// Block tile 64o x 64n, K chunks of 32, 4x4 microtile per thread.
// ---------------------------------------------------------------------------
template<bool TRANS_OUT, bool HAS_BIAS>
__global__ __launch_bounds__(256) void gemm_wx(const float* __restrict__ W,
                                               const float* __restrict__ X,
                                               const float* __restrict__ bias,
                                               float* __restrict__ OUT, int M) {
  __shared__ float w_s[32][68];  // [k][o], pad 68 keeps float4 reads aligned
  __shared__ float x_s[32][68];  // [k][n]
  const int b  = blockIdx.z;
  const int o0 = blockIdx.y * 64;
  const int n0 = blockIdx.x * 64;
  const int t  = threadIdx.x;
  const int og = t & 15, ng = t >> 4;
  float acc[4][4] = {};
  const float* Xb = X + (size_t)b * CDIM * NDIM;

  for (int k0 = 0; k0 < CDIM; k0 += 32) {
    // stage W tile: 64 o x 32 k (transposed into [k][o])
    {
      const int o_l = t >> 3, k4 = (t & 7) << 2;
      float4 wa = *(const float4*)&W[(size_t)(o0 + o_l) * CDIM + k0 + k4];
      w_s[k4 + 0][o_l] = wa.x; w_s[k4 + 1][o_l] = wa.y;
      w_s[k4 + 2][o_l] = wa.z; w_s[k4 + 3][o_l] = wa.w;
      float4 wb = *(const float4*)&W[(size_t)(o0 + o_l + 32) * CDIM + k0 + k4];
      w_s[k4 + 0][o_l + 32] = wb.x; w_s[k4 + 1][o_l + 32] = wb.y;
      w_s[k4 + 2][o_l + 32] = wb.z; w_s[k4 + 3][o_l + 32] = wb.w;
      // stage X tile: 32 k x 64 n
      const int k_l = t >> 4, n4 = (t & 15) << 2;
      float4 xa = *(const float4*)&Xb[(size_t)(k0 + k_l) * NDIM + n0 + n4];
      x_s[k_l][n4 + 0] = xa.x; x_s[k_l][n4 + 1] = xa.y;
      x_s[k_l][n4 + 2] = xa.z; x_s[k_l][n4 + 3] = xa.w;
      float4 xb4 = *(const float4*)&Xb[(size_t)(k0 + k_l + 16) * NDIM + n0 + n4];
      x_s[k_l + 16][n4 + 0] = xb4.x; x_s[k_l + 16][n4 + 1] = xb4.y;
      x_s[k_l + 16][n4 + 2] = xb4.z; x_s[k_l + 16][n4 + 3] = xb4.w;
    }
    __syncthreads();
#pragma unroll
    for (int k = 0; k < 32; ++k) {
      float4 a  = *(const float4*)&w_s[k][og << 2];
      float4 bb = *(const float4*)&x_s[k][ng << 2];
      const float av[4]  = {a.x, a.y, a.z, a.w};
      const float bv4[4] = {bb.x, bb.y, bb.z, bb.w};
#pragma unroll
      for (int i = 0; i < 4; ++i)
#pragma unroll
        for (int j = 0; j < 4; ++j)
          acc[i][j] += av[i] * bv4[j];
    }
    __syncthreads();
  }

  if (TRANS_OUT) {
#pragma unroll
    for (int j = 0; j < 4; ++j) {
      float4 val = make_float4(acc[0][j], acc[1][j], acc[2][j], acc[3][j]);
      *(float4*)&OUT[((size_t)b * NDIM + n0 + (ng << 2) + j) * C4DIM + o0 + (og << 2)] = val;
    }
  } else {
#pragma unroll
    for (int i = 0; i < 4; ++i) {
      const int o = o0 + (og << 2) + i;
      const float bs = HAS_BIAS ? bias[o] : 0.f;
      float4 val = make_float4(acc[i][0] + bs, acc[i][1] + bs,
                               acc[i][2] + bs, acc[i][3] + bs);
      *(float4*)&OUT[((size_t)b * M + o) * NDIM + n0 + (ng << 2)] = val;
    }
  }
}

// ---------------------------------------------------------------------------
// Attention: per block = (b, 32 query rows).  For each j-tile of 32:
//   phase A: w[ii][jj] = exp(-sqrt(max(sq_i - 2 q_i.q_j + sq_j, 0)))
//   phase B: acc[c][ii] += w[ii][jj] * v[c][jj]
// Final: x_r[b][c][i] = acc / sum_j w.  No online max needed: diagonal gives
// d2 == 0 (same fp32 summation order for sq and dot), so -l2 <= 0 always.
// ---------------------------------------------------------------------------
__global__ __launch_bounds__(256) void attn_kernel(const float* __restrict__ qT,
                                                   const float* __restrict__ V,
                                                   float* __restrict__ XR) {
  __shared__ float q_is[32][65];   // odd pad: conflict-free b32 reads
  __shared__ float q_js[32][65];
  __shared__ float v_s[32][257];   // [jj][c], odd pad
  __shared__ float w_s[32][36];    // [jj][ii], pad 36 keeps float4 aligned
  __shared__ float sq_is[32];
  __shared__ float sq_js[32];
  __shared__ float sumw_s[32];

  const int b  = blockIdx.y;
  const int i0 = blockIdx.x * 32;
  const int t  = threadIdx.x;
  const int cg = t & 31;   // phase B: owns channels cg + 32m
  const int ig = t >> 5;   // phase B: owns queries 4*ig .. 4*ig+3
  const float* qTb = qT + (size_t)b * NDIM * C4DIM;
  const float* Vb  = V + (size_t)b * CDIM * NDIM;

  { // load q_is: 32 rows x 64, 8 floats/thread
    const int ii = t >> 3, cc0 = (t & 7) << 3;
    float4 a = *(const float4*)&qTb[(size_t)(i0 + ii) * C4DIM + cc0];
    float4 c4 = *(const float4*)&qTb[(size_t)(i0 + ii) * C4DIM + cc0 + 4];
    q_is[ii][cc0 + 0] = a.x;  q_is[ii][cc0 + 1] = a.y;
    q_is[ii][cc0 + 2] = a.z;  q_is[ii][cc0 + 3] = a.w;
    q_is[ii][cc0 + 4] = c4.x; q_is[ii][cc0 + 5] = c4.y;
    q_is[ii][cc0 + 6] = c4.z; q_is[ii][cc0 + 7] = c4.w;
  }
  __syncthreads();
  if (t < 32) {
    float s = 0.f;
    for (int cc = 0; cc < 64; ++cc) { const float qv = q_is[t][cc]; s += qv * qv; }
    sq_is[t] = s;
  }
  // (visibility of sq_is guaranteed by the barrier after first-tile staging)

  float acc[4][8] = {};
  float sumw_acc = 0.f;

  for (int j0 = 0; j0 < NDIM; j0 += 32) {
    { // stage q_js
      const int ii = t >> 3, cc0 = (t & 7) << 3;
      float4 a = *(const float4*)&qTb[(size_t)(j0 + ii) * C4DIM + cc0];
      float4 c4 = *(const float4*)&qTb[(size_t)(j0 + ii) * C4DIM + cc0 + 4];
      q_js[ii][cc0 + 0] = a.x;  q_js[ii][cc0 + 1] = a.y;
      q_js[ii][cc0 + 2] = a.z;  q_js[ii][cc0 + 3] = a.w;
      q_js[ii][cc0 + 4] = c4.x; q_js[ii][cc0 + 5] = c4.y;
      q_js[ii][cc0 + 6] = c4.z; q_js[ii][cc0 + 7] = c4.w;
    }
    { // stage v_s[jj][c]: 32 j x 256 c, transposed scatter
      const int jj4 = (t & 7) << 2;
      const int cbase = t >> 3;
#pragma unroll
      for (int p = 0; p < 8; ++p) {
        const int c = cbase + (p << 5);
        float4 vv = *(const float4*)&Vb[(size_t)c * NDIM + j0 + jj4];
        v_s[jj4 + 0][c] = vv.x; v_s[jj4 + 1][c] = vv.y;
        v_s[jj4 + 2][c] = vv.z; v_s[jj4 + 3][c] = vv.w;
      }
    }
    __syncthreads();
    if (t < 32) {
      float s = 0.f;
      for (int cc = 0; cc < 64; ++cc) { const float qv = q_js[t][cc]; s += qv * qv; }
      sq_js[t] = s;
    }
    __syncthreads();

    // phase A: 1024 pairs, 4 per thread
#pragma unroll
    for (int k = 0; k < 4; ++k) {
      const int p  = t + (k << 8);
      const int ii = p >> 5, jj = p & 31;
      float dot = 0.f;
#pragma unroll 8
      for (int cc = 0; cc < 64; ++cc) dot += q_is[ii][cc] * q_js[jj][cc];
      float d2 = sq_is[ii] - 2.f * dot + sq_js[jj];
      d2 = fmaxf(d2, 0.f);
      w_s[jj][ii] = __expf(-sqrtf(d2));
    }
    __syncthreads();

    if (t < 32) {  // running row-sums of w (threads 0..31 own ii = t)
#pragma unroll
      for (int jj = 0; jj < 32; ++jj) sumw_acc += w_s[jj][t];
    }

    // phase B: register outer product, 4 ii x 8 c per thread
#pragma unroll 4
    for (int jj = 0; jj < 32; ++jj) {
      float4 w4 = *(const float4*)&w_s[jj][ig << 2];
      const float wv4[4] = {w4.x, w4.y, w4.z, w4.w};
      float vm[8];
#pragma unroll
      for (int m = 0; m < 8; ++m) vm[m] = v_s[jj][cg + (m << 5)];
#pragma unroll
      for (int q = 0; q < 4; ++q)
#pragma unroll
        for (int m = 0; m < 8; ++m)
          acc[q][m] += wv4[q] * vm[m];
    }
    __syncthreads();
  }

  if (t < 32) sumw_s[t] = sumw_acc;
  __syncthreads();

#pragma unroll
  for (int q = 0; q < 4; ++q) {
    const float inv = 1.f / sumw_s[(ig << 2) + q];
    const int i = i0 + (ig << 2) + q;
#pragma unroll
    for (int m = 0; m < 8; ++m) {
      const int c = cg + (m << 5);
      XR[((size_t)b * CDIM + c) * NDIM + i] = acc[q][m] * inv;
    }
  }
}

// ---------------------------------------------------------------------------
// BatchNorm statistics: one block per channel, biased var over (B, N).
// Produces scale[c] = gamma*rsqrt(var+eps), shift[c] = beta - mean*scale.
// ---------------------------------------------------------------------------
__global__ __launch_bounds__(256) void bnstats_kernel(const float* __restrict__ T,
                                                      const float* __restrict__ gamma,
                                                      const float* __restrict__ beta,
                                                      float* __restrict__ scale,
                                                      float* __restrict__ shift) {
  const int c = blockIdx.x, t = threadIdx.x;
  float s = 0.f, ss = 0.f;
  for (int b = 0; b < BDIM; ++b) {
    const float* row = T + ((size_t)b * CDIM + c) * NDIM;
    for (int n = (t << 2); n < NDIM; n += 1024) {
      float4 v = *(const float4*)&row[n];
      s  += v.x + v.y + v.z + v.w;
      ss += v.x * v.x + v.y * v.y + v.z * v.z + v.w * v.w;
    }
  }
#pragma unroll
  for (int off = 32; off > 0; off >>= 1) {
    s  += __shfl_down(s, off);
    ss += __shfl_down(ss, off);
  }
  __shared__ float rs[4], rss[4];
  if ((t & 63) == 0) { rs[t >> 6] = s; rss[t >> 6] = ss; }
  __syncthreads();
  if (t == 0) {
    s  = rs[0] + rs[1] + rs[2] + rs[3];
    ss = rss[0] + rss[1] + rss[2] + rss[3];
    const float cnt = (float)(BDIM * NDIM);
    const float mean = s / cnt;
    const float var = fmaxf(ss / cnt - mean * mean, 0.f);
    const float sc = gamma[c] * rsqrtf(var + 1e-5f);
    scale[c] = sc;
    shift[c] = beta[c] - mean * sc;
  }
}

// ---------------------------------------------------------------------------
// Epilogue: out = x + relu(t*scale + shift), in-place on d_out (t lives there).
// ---------------------------------------------------------------------------
__global__ __launch_bounds__(256) void final_kernel(const float* __restrict__ x,
                                                    const float* __restrict__ scale,
                                                    const float* __restrict__ shift,
                                                    float* __restrict__ out) {
  const size_t idx = ((size_t)blockIdx.x * 256 + threadIdx.x) << 2;
  const int c = (int)((idx >> 11) & 255);
  float4 xv = *(const float4*)&x[idx];
  float4 tv = *(const float4*)&out[idx];
  const float sc = scale[c], sh = shift[c];
  float4 r;
  r.x = xv.x + fmaxf(tv.x * sc + sh, 0.f);
  r.y = xv.y + fmaxf(tv.y * sc + sh, 0.f);
  r.z = xv.z + fmaxf(tv.z * sc + sh, 0.f);
  r.w = xv.w + fmaxf(tv.w * sc + sh, 0.f);
  *(float4*)&out[idx] = r;
}

extern "C" void kernel_launch(void* const* d_in, const int* in_sizes, int n_in,
                              void* d_out, int out_size, void* d_ws, size_t ws_size,
                              hipStream_t stream) {
  const float* x     = (const float*)d_in[0];
  const float* wq    = (const float*)d_in[1];
  const float* wv    = (const float*)d_in[2];
  const float* bv    = (const float*)d_in[3];
  const float* wt    = (const float*)d_in[4];
  const float* bt    = (const float*)d_in[5];
  const float* gamma = (const float*)d_in[6];
  const float* beta  = (const float*)d_in[7];
  float* out = (float*)d_out;
  char* ws = (char*)d_ws;

  float* qT    = (float*)(ws);                    // [B][N][64]   4 MB
  float* v     = (float*)(ws + ((size_t)4  << 20)); // [B][C][N]  16 MB
  float* xr    = (float*)(ws + ((size_t)20 << 20)); // [B][C][N]  16 MB
  float* scale = (float*)(ws + ((size_t)36 << 20)); // [256]
  float* shift = scale + 256;

  // q (transposed) and v
  gemm_wx<true,  false><<<dim3(NDIM / 64, 1,         BDIM), 256, 0, stream>>>(wq, x, nullptr, qT, C4DIM);
  gemm_wx<false, true ><<<dim3(NDIM / 64, CDIM / 64, BDIM), 256, 0, stream>>>(wv, x, bv, v, CDIM);
  // L2 attention -> x_r
  attn_kernel<<<dim3(NDIM / 32, BDIM), 256, 0, stream>>>(qT, v, xr);
  // t = wt*x_r + bt  (stored in d_out, finished in place)
  gemm_wx<false, true ><<<dim3(NDIM / 64, CDIM / 64, BDIM), 256, 0, stream>>>(wt, xr, bt, out, CDIM);
  bnstats_kernel<<<dim3(CDIM), 256, 0, stream>>>(out, gamma, beta, scale, shift);
  final_kernel<<<dim3((BDIM * CDIM * NDIM) / (256 * 4)), 256, 0, stream>>>(x, scale, shift, out);
}

// Round 2
// 298.303 us; speedup vs baseline: 2.2207x; 2.2207x over previous
//
#include <hip/hip_runtime.h>
#include <math.h>

#define BDIM 8
#define CDIM 256
#define C4DIM 64
#define NDIM 2048

typedef short bf16x8 __attribute__((ext_vector_type(8)));
typedef short short4v __attribute__((ext_vector_type(4)));
typedef float f32x4 __attribute__((ext_vector_type(4)));

__device__ inline short f2bf(float f) {
  unsigned u; __builtin_memcpy(&u, &f, 4);
  u += 0x7fffu + ((u >> 16) & 1u);           // RNE (NaN-unsafe, inputs are finite)
  return (short)(u >> 16);
}
__device__ inline float bf2f(short s) {
  unsigned u = ((unsigned)(unsigned short)s) << 16;
  float f; __builtin_memcpy(&f, &u, 4);
  return f;
}

// ---------------------------------------------------------------------------
// GEMM: OUT = W (M x 256) * X[b] (256 x N)  (+bias)
// TRANS_OUT: OUT[b][n][o] (row 64, qT); else OUT[b][o][n]. BF16_OUT: pack bf16.
// ---------------------------------------------------------------------------
template<bool TRANS_OUT, bool HAS_BIAS, bool BF16_OUT>
__global__ __launch_bounds__(256) void gemm_wx(const float* __restrict__ W,
                                               const float* __restrict__ X,
                                               const float* __restrict__ bias,
                                               void* __restrict__ OUTP, int M) {
  __shared__ float w_s[32][68];
  __shared__ float x_s[32][68];
  const int b  = blockIdx.z;
  const int o0 = blockIdx.y * 64;
  const int n0 = blockIdx.x * 64;
  const int t  = threadIdx.x;
  const int og = t & 15, ng = t >> 4;
  float acc[4][4] = {};
  const float* Xb = X + (size_t)b * CDIM * NDIM;

  for (int k0 = 0; k0 < CDIM; k0 += 32) {
    {
      const int o_l = t >> 3, k4 = (t & 7) << 2;
      float4 wa = *(const float4*)&W[(size_t)(o0 + o_l) * CDIM + k0 + k4];
      w_s[k4 + 0][o_l] = wa.x; w_s[k4 + 1][o_l] = wa.y;
      w_s[k4 + 2][o_l] = wa.z; w_s[k4 + 3][o_l] = wa.w;
      float4 wb = *(const float4*)&W[(size_t)(o0 + o_l + 32) * CDIM + k0 + k4];
      w_s[k4 + 0][o_l + 32] = wb.x; w_s[k4 + 1][o_l + 32] = wb.y;
      w_s[k4 + 2][o_l + 32] = wb.z; w_s[k4 + 3][o_l + 32] = wb.w;
      const int k_l = t >> 4, n4 = (t & 15) << 2;
      float4 xa = *(const float4*)&Xb[(size_t)(k0 + k_l) * NDIM + n0 + n4];
      x_s[k_l][n4 + 0] = xa.x; x_s[k_l][n4 + 1] = xa.y;
      x_s[k_l][n4 + 2] = xa.z; x_s[k_l][n4 + 3] = xa.w;
      float4 xb4 = *(const float4*)&Xb[(size_t)(k0 + k_l + 16) * NDIM + n0 + n4];
      x_s[k_l + 16][n4 + 0] = xb4.x; x_s[k_l + 16][n4 + 1] = xb4.y;
      x_s[k_l + 16][n4 + 2] = xb4.z; x_s[k_l + 16][n4 + 3] = xb4.w;
    }
    __syncthreads();
#pragma unroll
    for (int k = 0; k < 32; ++k) {
      float4 a  = *(const float4*)&w_s[k][og << 2];
      float4 bb = *(const float4*)&x_s[k][ng << 2];
      const float av[4]  = {a.x, a.y, a.z, a.w};
      const float bv4[4] = {bb.x, bb.y, bb.z, bb.w};
#pragma unroll
      for (int i = 0; i < 4; ++i)
#pragma unroll
        for (int j = 0; j < 4; ++j)
          acc[i][j] += av[i] * bv4[j];
    }
    __syncthreads();
  }

  if (TRANS_OUT) {
#pragma unroll
    for (int j = 0; j < 4; ++j) {
      const size_t base = ((size_t)b * NDIM + n0 + (ng << 2) + j) * C4DIM + o0 + (og << 2);
      if (BF16_OUT) {
        short4v s4 = {f2bf(acc[0][j]), f2bf(acc[1][j]), f2bf(acc[2][j]), f2bf(acc[3][j])};
        *(short4v*)&((short*)OUTP)[base] = s4;
      } else {
        *(float4*)&((float*)OUTP)[base] =
            make_float4(acc[0][j], acc[1][j], acc[2][j], acc[3][j]);
      }
    }
  } else {
#pragma unroll
    for (int i = 0; i < 4; ++i) {
      const int o = o0 + (og << 2) + i;
      const float bs = HAS_BIAS ? bias[o] : 0.f;
      const size_t base = ((size_t)b * M + o) * NDIM + n0 + (ng << 2);
      if (BF16_OUT) {
        short4v s4 = {f2bf(acc[i][0] + bs), f2bf(acc[i][1] + bs),
                      f2bf(acc[i][2] + bs), f2bf(acc[i][3] + bs)};
        *(short4v*)&((short*)OUTP)[base] = s4;
      } else {
        *(float4*)&((float*)OUTP)[base] = make_float4(
            acc[i][0] + bs, acc[i][1] + bs, acc[i][2] + bs, acc[i][3] + bs);
      }
    }
  }
}

// ---------------------------------------------------------------------------
// sq[b][n] = sum_c qT_bf16[b][n][c]^2  (fp32, from the bf16-rounded q so the
// attention diagonal d2 is ~0 to accumulation-order noise)
// ---------------------------------------------------------------------------
__global__ __launch_bounds__(256) void sq_kernel(const short* __restrict__ qT,
                                                 float* __restrict__ sq) {
  const int idx = blockIdx.x * 256 + threadIdx.x;
  const bf16x8* row = (const bf16x8*)(qT + (size_t)idx * C4DIM);
  float s = 0.f;
#pragma unroll
  for (int k = 0; k < 8; ++k) {
    bf16x8 v = row[k];
#pragma unroll
    for (int e = 0; e < 8; ++e) { float q = bf2f(v[e]); s = fmaf(q, q, s); }
  }
  sq[idx] = s;
}

// ---------------------------------------------------------------------------
// MFMA L2 attention. Block = (b, 16 queries), 4 waves; wave w owns j-quarter
// [w*512, w*512+512). Per j-step of 32:
//   gram: S[i16][j16] x2 via mfma_16x16x32_bf16 (A=qI frags hoisted, B=qJ)
//   w = exp(-sqrt(max(sq_i - 2S + sq_j, 0)))  -> bf16 -> LDS [i][j]
//   PV: acc[c16][i16] += v[c][j32] * w^T  (16 c-tiles, B-frag from LDS)
// Partials across waves combine linearly (no softmax max needed: weights<=1,
// diagonal ~1). LDS tree-combine + normalize in wave 0.
// ---------------------------------------------------------------------------
__global__ __launch_bounds__(256) void attn_mfma(const short* __restrict__ qT,
                                                 const short* __restrict__ Vb16,
                                                 const float* __restrict__ sq,
                                                 float* __restrict__ XR) {
  __shared__ short w_lds[4][2][16][40];   // [wave][dbuf][i][j], 80B rows (16B-aligned)
  __shared__ float comb[2][256][16];      // partial-acc combine
  __shared__ float sums_lds[4][16];

  const int b  = blockIdx.y;
  const int i0 = blockIdx.x * 16;
  const int t  = threadIdx.x;
  const int w  = t >> 6;
  const int l  = t & 63;
  const int il = l & 15;     // MFMA column index (i or j local)
  const int g  = l >> 4;     // lane group

  const short* qTb = qT + (size_t)b * NDIM * C4DIM;
  const short* Vbb = Vb16 + (size_t)b * CDIM * NDIM;
  const float* sqb = sq + (size_t)b * NDIM;

  // hoisted qI A-fragments (c chunks 0..31, 32..63)
  const bf16x8 aQ0 = *(const bf16x8*)&qTb[(size_t)(i0 + il) * C4DIM + g * 8];
  const bf16x8 aQ1 = *(const bf16x8*)&qTb[(size_t)(i0 + il) * C4DIM + 32 + g * 8];
  float sqi[4];
#pragma unroll
  for (int r = 0; r < 4; ++r) sqi[r] = sqb[i0 + g * 4 + r];

  f32x4 acc[16];
#pragma unroll
  for (int ct = 0; ct < 16; ++ct) acc[ct] = {0.f, 0.f, 0.f, 0.f};
  float sumw[4] = {0.f, 0.f, 0.f, 0.f};

  const int j_begin = w * (NDIM / 4);
  for (int j0 = j_begin; j0 < j_begin + NDIM / 4; j0 += 32) {
    const int p = (j0 >> 5) & 1;
#pragma unroll
    for (int h = 0; h < 2; ++h) {
      const size_t jrow = (size_t)(j0 + h * 16 + il) * C4DIM;
      bf16x8 b0 = *(const bf16x8*)&qTb[jrow + g * 8];
      bf16x8 b1 = *(const bf16x8*)&qTb[jrow + 32 + g * 8];
      f32x4 s = {0.f, 0.f, 0.f, 0.f};
      s = __builtin_amdgcn_mfma_f32_16x16x32_bf16(aQ0, b0, s, 0, 0, 0);
      s = __builtin_amdgcn_mfma_f32_16x16x32_bf16(aQ1, b1, s, 0, 0, 0);
      const float sqj = sqb[j0 + h * 16 + il];
#pragma unroll
      for (int r = 0; r < 4; ++r) {
        float d2 = fmaxf(fmaf(-2.f, s[r], sqi[r] + sqj), 0.f);
        float wv = __expf(-sqrtf(d2));
        sumw[r] += wv;
        w_lds[w][p][g * 4 + r][h * 16 + il] = f2bf(wv);
      }
    }
    const bf16x8 bW = *(const bf16x8*)&w_lds[w][p][il][g * 8];
#pragma unroll
    for (int ct = 0; ct < 16; ++ct) {
      bf16x8 aV = *(const bf16x8*)&Vbb[(size_t)(ct * 16 + il) * NDIM + j0 + g * 8];
      acc[ct] = __builtin_amdgcn_mfma_f32_16x16x32_bf16(aV, bW, acc[ct], 0, 0, 0);
    }
  }

  // reduce sumw across the 16 j-lanes (same g => same i-set)
#pragma unroll
  for (int m = 1; m <= 8; m <<= 1)
#pragma unroll
    for (int r = 0; r < 4; ++r) sumw[r] += __shfl_xor(sumw[r], m, 64);
  if (il == 0) {
#pragma unroll
    for (int r = 0; r < 4; ++r) sums_lds[w][g * 4 + r] = sumw[r];
  }
  if (w >= 2) {
    const int pp = w - 2;
#pragma unroll
    for (int ct = 0; ct < 16; ++ct)
#pragma unroll
      for (int r = 0; r < 4; ++r) comb[pp][ct * 16 + g * 4 + r][il] = acc[ct][r];
  }
  __syncthreads();
  if (w < 2) {
#pragma unroll
    for (int ct = 0; ct < 16; ++ct)
#pragma unroll
      for (int r = 0; r < 4; ++r) acc[ct][r] += comb[w][ct * 16 + g * 4 + r][il];
  }
  __syncthreads();
  if (w == 1) {
#pragma unroll
    for (int ct = 0; ct < 16; ++ct)
#pragma unroll
      for (int r = 0; r < 4; ++r) comb[0][ct * 16 + g * 4 + r][il] = acc[ct][r];
  }
  __syncthreads();
  if (w == 0) {
    const float stot = sums_lds[0][il] + sums_lds[1][il] + sums_lds[2][il] + sums_lds[3][il];
    const float inv = 1.f / stot;
#pragma unroll
    for (int ct = 0; ct < 16; ++ct)
#pragma unroll
      for (int r = 0; r < 4; ++r) {
        const int c = ct * 16 + g * 4 + r;
        XR[((size_t)b * CDIM + c) * NDIM + i0 + il] =
            (acc[ct][r] + comb[0][c][il]) * inv;
      }
  }
}

// ---------------------------------------------------------------------------
// BatchNorm statistics (unchanged)
// ---------------------------------------------------------------------------
__global__ __launch_bounds__(256) void bnstats_kernel(const float* __restrict__ T,
                                                      const float* __restrict__ gamma,
                                                      const float* __restrict__ beta,
                                                      float* __restrict__ scale,
                                                      float* __restrict__ shift) {
  const int c = blockIdx.x, t = threadIdx.x;
  float s = 0.f, ss = 0.f;
  for (int b = 0; b < BDIM; ++b) {
    const float* row = T + ((size_t)b * CDIM + c) * NDIM;
    for (int n = (t << 2); n < NDIM; n += 1024) {
      float4 v = *(const float4*)&row[n];
      s  += v.x + v.y + v.z + v.w;
      ss += v.x * v.x + v.y * v.y + v.z * v.z + v.w * v.w;
    }
  }
#pragma unroll
  for (int off = 32; off > 0; off >>= 1) {
    s  += __shfl_down(s, off);
    ss += __shfl_down(ss, off);
  }
  __shared__ float rs[4], rss[4];
  if ((t & 63) == 0) { rs[t >> 6] = s; rss[t >> 6] = ss; }
  __syncthreads();
  if (t == 0) {
    s  = rs[0] + rs[1] + rs[2] + rs[3];
    ss = rss[0] + rss[1] + rss[2] + rss[3];
    const float cnt = (float)(BDIM * NDIM);
    const float mean = s / cnt;
    const float var = fmaxf(ss / cnt - mean * mean, 0.f);
    const float sc = gamma[c] * rsqrtf(var + 1e-5f);
    scale[c] = sc;
    shift[c] = beta[c] - mean * sc;
  }
}

__global__ __launch_bounds__(256) void final_kernel(const float* __restrict__ x,
                                                    const float* __restrict__ scale,
                                                    const float* __restrict__ shift,
                                                    float* __restrict__ out) {
  const size_t idx = ((size_t)blockIdx.x * 256 + threadIdx.x) << 2;
  const int c = (int)((idx >> 11) & 255);
  float4 xv = *(const float4*)&x[idx];
  float4 tv = *(const float4*)&out[idx];
  const float sc = scale[c], sh = shift[c];
  float4 r;
  r.x = xv.x + fmaxf(tv.x * sc + sh, 0.f);
  r.y = xv.y + fmaxf(tv.y * sc + sh, 0.f);
  r.z = xv.z + fmaxf(tv.z * sc + sh, 0.f);
  r.w = xv.w + fmaxf(tv.w * sc + sh, 0.f);
  *(float4*)&out[idx] = r;
}

extern "C" void kernel_launch(void* const* d_in, const int* in_sizes, int n_in,
                              void* d_out, int out_size, void* d_ws, size_t ws_size,
                              hipStream_t stream) {
  const float* x     = (const float*)d_in[0];
  const float* wq    = (const float*)d_in[1];
  const float* wv    = (const float*)d_in[2];
  const float* bv    = (const float*)d_in[3];
  const float* wt    = (const float*)d_in[4];
  const float* bt    = (const float*)d_in[5];
  const float* gamma = (const float*)d_in[6];
  const float* beta  = (const float*)d_in[7];
  float* out = (float*)d_out;
  char* ws = (char*)d_ws;

  short* qT    = (short*)(ws);                      // [B][N][64] bf16   2 MB
  short* vbf   = (short*)(ws + ((size_t)2  << 20)); // [B][C][N]  bf16   8 MB
  float* xr    = (float*)(ws + ((size_t)10 << 20)); // [B][C][N]  f32   16 MB
  float* sq    = (float*)(ws + ((size_t)26 << 20)); // [B][N]           64 KB
  float* scale = (float*)(ws + ((size_t)27 << 20));
  float* shift = scale + 256;

  gemm_wx<true,  false, true ><<<dim3(NDIM / 64, 1,         BDIM), 256, 0, stream>>>(wq, x, nullptr, qT, C4DIM);
  gemm_wx<false, true,  true ><<<dim3(NDIM / 64, CDIM / 64, BDIM), 256, 0, stream>>>(wv, x, bv, vbf, CDIM);
  sq_kernel<<<dim3(BDIM * NDIM / 256), 256, 0, stream>>>(qT, sq);
  attn_mfma<<<dim3(NDIM / 16, BDIM), 256, 0, stream>>>(qT, vbf, sq, xr);
  gemm_wx<false, true,  false><<<dim3(NDIM / 64, CDIM / 64, BDIM), 256, 0, stream>>>(wt, xr, bt, out, CDIM);
  bnstats_kernel<<<dim3(CDIM), 256, 0, stream>>>(out, gamma, beta, scale, shift);
  final_kernel<<<dim3((BDIM * CDIM * NDIM) / (256 * 4)), 256, 0, stream>>>(x, scale, shift, out);
}

// Round 3
// 181.702 us; speedup vs baseline: 3.6457x; 1.6417x over previous
//
#include <hip/hip_runtime.h>
#include <math.h>

#define BDIM 8
#define CDIM 256
#define C4DIM 64
#define NDIM 2048

typedef short bf16x8 __attribute__((ext_vector_type(8)));
typedef short short4v __attribute__((ext_vector_type(4)));
typedef float f32x4 __attribute__((ext_vector_type(4)));

__device__ inline short f2bf(float f) {
  unsigned u; __builtin_memcpy(&u, &f, 4);
  u += 0x7fffu + ((u >> 16) & 1u);           // RNE (NaN-unsafe, inputs are finite)
  return (short)(u >> 16);
}
__device__ inline float bf2f(short s) {
  unsigned u = ((unsigned)(unsigned short)s) << 16;
  float f; __builtin_memcpy(&f, &u, 4);
  return f;
}
__device__ inline unsigned pack2bf(float a, float b) {
  return (unsigned)(unsigned short)f2bf(a) | ((unsigned)(unsigned short)f2bf(b) << 16);
}

// ---------------------------------------------------------------------------
// GEMM: OUT = W (M x 256) * X[b] (256 x N)  (+bias)   [unchanged, passing]
// ---------------------------------------------------------------------------
template<bool TRANS_OUT, bool HAS_BIAS, bool BF16_OUT>
__global__ __launch_bounds__(256) void gemm_wx(const float* __restrict__ W,
                                               const float* __restrict__ X,
                                               const float* __restrict__ bias,
                                               void* __restrict__ OUTP, int M) {
  __shared__ float w_s[32][68];
  __shared__ float x_s[32][68];
  const int b  = blockIdx.z;
  const int o0 = blockIdx.y * 64;
  const int n0 = blockIdx.x * 64;
  const int t  = threadIdx.x;
  const int og = t & 15, ng = t >> 4;
  float acc[4][4] = {};
  const float* Xb = X + (size_t)b * CDIM * NDIM;

  for (int k0 = 0; k0 < CDIM; k0 += 32) {
    {
      const int o_l = t >> 3, k4 = (t & 7) << 2;
      float4 wa = *(const float4*)&W[(size_t)(o0 + o_l) * CDIM + k0 + k4];
      w_s[k4 + 0][o_l] = wa.x; w_s[k4 + 1][o_l] = wa.y;
      w_s[k4 + 2][o_l] = wa.z; w_s[k4 + 3][o_l] = wa.w;
      float4 wb = *(const float4*)&W[(size_t)(o0 + o_l + 32) * CDIM + k0 + k4];
      w_s[k4 + 0][o_l + 32] = wb.x; w_s[k4 + 1][o_l + 32] = wb.y;
      w_s[k4 + 2][o_l + 32] = wb.z; w_s[k4 + 3][o_l + 32] = wb.w;
      const int k_l = t >> 4, n4 = (t & 15) << 2;
      float4 xa = *(const float4*)&Xb[(size_t)(k0 + k_l) * NDIM + n0 + n4];
      x_s[k_l][n4 + 0] = xa.x; x_s[k_l][n4 + 1] = xa.y;
      x_s[k_l][n4 + 2] = xa.z; x_s[k_l][n4 + 3] = xa.w;
      float4 xb4 = *(const float4*)&Xb[(size_t)(k0 + k_l + 16) * NDIM + n0 + n4];
      x_s[k_l + 16][n4 + 0] = xb4.x; x_s[k_l + 16][n4 + 1] = xb4.y;
      x_s[k_l + 16][n4 + 2] = xb4.z; x_s[k_l + 16][n4 + 3] = xb4.w;
    }
    __syncthreads();
#pragma unroll
    for (int k = 0; k < 32; ++k) {
      float4 a  = *(const float4*)&w_s[k][og << 2];
      float4 bb = *(const float4*)&x_s[k][ng << 2];
      const float av[4]  = {a.x, a.y, a.z, a.w};
      const float bv4[4] = {bb.x, bb.y, bb.z, bb.w};
#pragma unroll
      for (int i = 0; i < 4; ++i)
#pragma unroll
        for (int j = 0; j < 4; ++j)
          acc[i][j] += av[i] * bv4[j];
    }
    __syncthreads();
  }

  if (TRANS_OUT) {
#pragma unroll
    for (int j = 0; j < 4; ++j) {
      const size_t base = ((size_t)b * NDIM + n0 + (ng << 2) + j) * C4DIM + o0 + (og << 2);
      if (BF16_OUT) {
        short4v s4 = {f2bf(acc[0][j]), f2bf(acc[1][j]), f2bf(acc[2][j]), f2bf(acc[3][j])};
        *(short4v*)&((short*)OUTP)[base] = s4;
      } else {
        *(float4*)&((float*)OUTP)[base] =
            make_float4(acc[0][j], acc[1][j], acc[2][j], acc[3][j]);
      }
    }
  } else {
#pragma unroll
    for (int i = 0; i < 4; ++i) {
      const int o = o0 + (og << 2) + i;
      const float bs = HAS_BIAS ? bias[o] : 0.f;
      const size_t base = ((size_t)b * M + o) * NDIM + n0 + (ng << 2);
      if (BF16_OUT) {
        short4v s4 = {f2bf(acc[i][0] + bs), f2bf(acc[i][1] + bs),
                      f2bf(acc[i][2] + bs), f2bf(acc[i][3] + bs)};
        *(short4v*)&((short*)OUTP)[base] = s4;
      } else {
        *(float4*)&((float*)OUTP)[base] = make_float4(
            acc[i][0] + bs, acc[i][1] + bs, acc[i][2] + bs, acc[i][3] + bs);
      }
    }
  }
}

// ---------------------------------------------------------------------------
// sq[b][n] = sum_c qT_bf16[b][n][c]^2  (fp32, from bf16-rounded q)
// ---------------------------------------------------------------------------
__global__ __launch_bounds__(256) void sq_kernel(const short* __restrict__ qT,
                                                 float* __restrict__ sq) {
  const int idx = blockIdx.x * 256 + threadIdx.x;
  const bf16x8* row = (const bf16x8*)(qT + (size_t)idx * C4DIM);
  float s = 0.f;
#pragma unroll
  for (int k = 0; k < 8; ++k) {
    bf16x8 v = row[k];
#pragma unroll
    for (int e = 0; e < 8; ++e) { float q = bf2f(v[e]); s = fmaf(q, q, s); }
  }
  sq[idx] = s;
}

// ---------------------------------------------------------------------------
// MFMA L2 attention v2.  Block = (b, 64 queries), 8 waves (512 thr).
// Wave w: i-subtile isub=w&3 (16 i's), c-half chalf=w>>2 (8 c-tiles).
// Per 32-j step (64 steps):
//  - V tile [256][32] + qJ tile [32][64] reg-staged into XOR-swizzled LDS,
//    double-buffered, loads for step t+1 issued before compute of t.
//  - Swapped gram S = mfma(qJ, qI): lane holds w[j= g*4+r+16h][i=il].
//  - w=exp(-sqrt(max(sq_i-2S+sq_j,0))), packed to bf16, redistributed
//    IN-REGISTER via 8 __shfl to form the PV B-fragment (no W LDS, no extra
//    barrier, gram duplicated across the two c-half waves).
//  - PV: acc[ct] = mfma(V_lds[ct], bW, acc[ct]), 8 c-tiles/wave.
// No online max needed (diagonal d2~0 -> w<=1, sum>=1); partials are linear.
// Each wave owns its full (isub, chalf) output: normalize + write.
// ---------------------------------------------------------------------------
__global__ __launch_bounds__(512) void attn_mfma(const short* __restrict__ qT,
                                                 const short* __restrict__ Vb16,
                                                 const float* __restrict__ sq,
                                                 float* __restrict__ XR) {
  __shared__ __align__(16) short vj[2][256 * 32];  // [c][j-slot swz], 16 KB each
  __shared__ __align__(16) short qj[2][32 * 64];   // [j][k-slot swz], 4 KB each

  const int b  = blockIdx.y;
  const int i0 = blockIdx.x * 64;
  const int t  = threadIdx.x;
  const int w  = t >> 6, l = t & 63;
  const int il = l & 15, g = l >> 4;
  const int isub = w & 3, chalf = w >> 2;

  const short* qTb = qT + (size_t)b * NDIM * C4DIM;
  const short* Vbb = Vb16 + (size_t)b * CDIM * NDIM;
  const float* sqb = sq + (size_t)b * NDIM;

  // hoisted qI B-fragments (col = i = il, k-chunks 0..31 / 32..63)
  const int iglob = i0 + isub * 16 + il;
  const bf16x8 bq0 = *(const bf16x8*)&qTb[(size_t)iglob * C4DIM + g * 8];
  const bf16x8 bq1 = *(const bf16x8*)&qTb[(size_t)iglob * C4DIM + 32 + g * 8];
  const float sqi = sqb[iglob];

  // staging maps (linear global source -> swizzled LDS dest), 2 V chunks/thread
  const int vc0 = t >> 2,           vs0 = t & 3;
  const int vc1 = 128 + (t >> 2),   vs1 = t & 3;
  const int vd0 = vc0 * 32 + ((vs0 ^ ((vc0 >> 1) & 3)) << 3);
  const int vd1 = vc1 * 32 + ((vs1 ^ ((vc1 >> 1) & 3)) << 3);
  const int qrow = t >> 3, qslot = t & 7;                       // waves 0..3 only
  const int qd = qrow * 64 + ((qslot ^ (qrow & 7)) << 3);

  f32x4 acc[8];
#pragma unroll
  for (int k = 0; k < 8; ++k) acc[k] = {0.f, 0.f, 0.f, 0.f};
  float sumw = 0.f;

  // ---- prologue: stage step 0 ----
  float sqc[8];
  {
    bf16x8 vr0 = *(const bf16x8*)&Vbb[(size_t)vc0 * NDIM + 0 + vs0 * 8];
    bf16x8 vr1 = *(const bf16x8*)&Vbb[(size_t)vc1 * NDIM + 0 + vs1 * 8];
    *(bf16x8*)&vj[0][vd0] = vr0;
    *(bf16x8*)&vj[0][vd1] = vr1;
    if (w < 4) {
      bf16x8 qr = *(const bf16x8*)&qTb[(size_t)(0 + qrow) * C4DIM + qslot * 8];
      *(bf16x8*)&qj[0][qd] = qr;
    }
#pragma unroll
    for (int h = 0; h < 2; ++h)
#pragma unroll
      for (int r = 0; r < 4; ++r) sqc[h * 4 + r] = sqb[0 + h * 16 + g * 4 + r];
  }
  __syncthreads();

  const int NT = NDIM / 32;
  for (int jt = 0; jt < NT; ++jt) {
    const int p = jt & 1;
    const short* vbuf = &vj[p][0];
    const short* qbuf = &qj[p][0];
    short* vbufN = &vj[p ^ 1][0];
    short* qbufN = &qj[p ^ 1][0];
    const int j0 = jt * 32;
    const bool has_next = (jt + 1 < NT);
    const int j0n = j0 + 32;

    // issue next-step global loads (latency hides under compute below)
    bf16x8 vr0, vr1, qr;
    float sqn[8];
    if (has_next) {
      vr0 = *(const bf16x8*)&Vbb[(size_t)vc0 * NDIM + j0n + vs0 * 8];
      vr1 = *(const bf16x8*)&Vbb[(size_t)vc1 * NDIM + j0n + vs1 * 8];
      if (w < 4) qr = *(const bf16x8*)&qTb[(size_t)(j0n + qrow) * C4DIM + qslot * 8];
#pragma unroll
      for (int h = 0; h < 2; ++h)
#pragma unroll
        for (int r = 0; r < 4; ++r) sqn[h * 4 + r] = sqb[j0n + h * 16 + g * 4 + r];
    }

    // ---- gram + softmax: w[j = 16h + 4g + r][i = il] ----
    unsigned pk[2][2];
#pragma unroll
    for (int h = 0; h < 2; ++h) {
      const int row = h * 16 + il;
      bf16x8 aJ0 = *(const bf16x8*)&qbuf[row * 64 + (((0 * 4 + g) ^ (il & 7)) << 3)];
      bf16x8 aJ1 = *(const bf16x8*)&qbuf[row * 64 + (((1 * 4 + g) ^ (il & 7)) << 3)];
      f32x4 s = {0.f, 0.f, 0.f, 0.f};
      s = __builtin_amdgcn_mfma_f32_16x16x32_bf16(aJ0, bq0, s, 0, 0, 0);
      s = __builtin_amdgcn_mfma_f32_16x16x32_bf16(aJ1, bq1, s, 0, 0, 0);
      float wv[4];
#pragma unroll
      for (int r = 0; r < 4; ++r) {
        float d2 = fmaxf(fmaf(-2.f, s[r], sqi + sqc[h * 4 + r]), 0.f);
        wv[r] = __expf(-sqrtf(d2));
        sumw += wv[r];
      }
      pk[h][0] = pack2bf(wv[0], wv[1]);
      pk[h][1] = pack2bf(wv[2], wv[3]);
    }

    // ---- in-register redistribution to PV B-fragment ----
    // dest lane (il,g) dword d needs j = 8g+2d,+1 -> src lane (il, (2g+(d>>1))&3),
    // packed pair (h = g>>1, p = d&1)
    union { unsigned u[4]; bf16x8 v; } bw;
#pragma unroll
    for (int d = 0; d < 4; ++d) {
      const int srcl = il + ((((g << 1) + (d >> 1)) & 3) << 4);
      unsigned v0 = (unsigned)__shfl((int)pk[0][d & 1], srcl, 64);
      unsigned v1 = (unsigned)__shfl((int)pk[1][d & 1], srcl, 64);
      bw.u[d] = (g >> 1) ? v1 : v0;
    }

    // ---- PV: 8 c-tiles for this wave's c-half ----
#pragma unroll
    for (int ctl = 0; ctl < 8; ++ctl) {
      const int c = (chalf * 8 + ctl) * 16 + il;
      bf16x8 aV = *(const bf16x8*)&vbuf[c * 32 + ((g ^ ((il >> 1) & 3)) << 3)];
      acc[ctl] = __builtin_amdgcn_mfma_f32_16x16x32_bf16(aV, bw.v, acc[ctl], 0, 0, 0);
    }

    // ---- write next-step staging into the other buffer, one barrier ----
    if (has_next) {
      *(bf16x8*)&vbufN[vd0] = vr0;
      *(bf16x8*)&vbufN[vd1] = vr1;
      if (w < 4) *(bf16x8*)&qbufN[qd] = qr;
#pragma unroll
      for (int k = 0; k < 8; ++k) sqc[k] = sqn[k];
    }
    __syncthreads();
  }

  // ---- normalize + write (each wave owns its (isub, chalf) block) ----
  sumw += __shfl_xor(sumw, 16, 64);
  sumw += __shfl_xor(sumw, 32, 64);
  const float inv = 1.f / sumw;
#pragma unroll
  for (int ctl = 0; ctl < 8; ++ctl) {
#pragma unroll
    for (int r = 0; r < 4; ++r) {
      const int c = (chalf * 8 + ctl) * 16 + g * 4 + r;
      XR[((size_t)b * CDIM + c) * NDIM + i0 + isub * 16 + il] = acc[ctl][r] * inv;
    }
  }
}

// ---------------------------------------------------------------------------
// BatchNorm statistics (unchanged)
// ---------------------------------------------------------------------------
__global__ __launch_bounds__(256) void bnstats_kernel(const float* __restrict__ T,
                                                      const float* __restrict__ gamma,
                                                      const float* __restrict__ beta,
                                                      float* __restrict__ scale,
                                                      float* __restrict__ shift) {
  const int c = blockIdx.x, t = threadIdx.x;
  float s = 0.f, ss = 0.f;
  for (int b = 0; b < BDIM; ++b) {
    const float* row = T + ((size_t)b * CDIM + c) * NDIM;
    for (int n = (t << 2); n < NDIM; n += 1024) {
      float4 v = *(const float4*)&row[n];
      s  += v.x + v.y + v.z + v.w;
      ss += v.x * v.x + v.y * v.y + v.z * v.z + v.w * v.w;
    }
  }
#pragma unroll
  for (int off = 32; off > 0; off >>= 1) {
    s  += __shfl_down(s, off);
    ss += __shfl_down(ss, off);
  }
  __shared__ float rs[4], rss[4];
  if ((t & 63) == 0) { rs[t >> 6] = s; rss[t >> 6] = ss; }
  __syncthreads();
  if (t == 0) {
    s  = rs[0] + rs[1] + rs[2] + rs[3];
    ss = rss[0] + rss[1] + rss[2] + rss[3];
    const float cnt = (float)(BDIM * NDIM);
    const float mean = s / cnt;
    const float var = fmaxf(ss / cnt - mean * mean, 0.f);
    const float sc = gamma[c] * rsqrtf(var + 1e-5f);
    scale[c] = sc;
    shift[c] = beta[c] - mean * sc;
  }
}

__global__ __launch_bounds__(256) void final_kernel(const float* __restrict__ x,
                                                    const float* __restrict__ scale,
                                                    const float* __restrict__ shift,
                                                    float* __restrict__ out) {
  const size_t idx = ((size_t)blockIdx.x * 256 + threadIdx.x) << 2;
  const int c = (int)((idx >> 11) & 255);
  float4 xv = *(const float4*)&x[idx];
  float4 tv = *(const float4*)&out[idx];
  const float sc = scale[c], sh = shift[c];
  float4 r;
  r.x = xv.x + fmaxf(tv.x * sc + sh, 0.f);
  r.y = xv.y + fmaxf(tv.y * sc + sh, 0.f);
  r.z = xv.z + fmaxf(tv.z * sc + sh, 0.f);
  r.w = xv.w + fmaxf(tv.w * sc + sh, 0.f);
  *(float4*)&out[idx] = r;
}

extern "C" void kernel_launch(void* const* d_in, const int* in_sizes, int n_in,
                              void* d_out, int out_size, void* d_ws, size_t ws_size,
                              hipStream_t stream) {
  const float* x     = (const float*)d_in[0];
  const float* wq    = (const float*)d_in[1];
  const float* wv    = (const float*)d_in[2];
  const float* bv    = (const float*)d_in[3];
  const float* wt    = (const float*)d_in[4];
  const float* bt    = (const float*)d_in[5];
  const float* gamma = (const float*)d_in[6];
  const float* beta  = (const float*)d_in[7];
  float* out = (float*)d_out;
  char* ws = (char*)d_ws;

  short* qT    = (short*)(ws);                      // [B][N][64] bf16   2 MB
  short* vbf   = (short*)(ws + ((size_t)2  << 20)); // [B][C][N]  bf16   8 MB
  float* xr    = (float*)(ws + ((size_t)10 << 20)); // [B][C][N]  f32   16 MB
  float* sq    = (float*)(ws + ((size_t)26 << 20)); // [B][N]           64 KB
  float* scale = (float*)(ws + ((size_t)27 << 20));
  float* shift = scale + 256;

  gemm_wx<true,  false, true ><<<dim3(NDIM / 64, 1,         BDIM), 256, 0, stream>>>(wq, x, nullptr, qT, C4DIM);
  gemm_wx<false, true,  true ><<<dim3(NDIM / 64, CDIM / 64, BDIM), 256, 0, stream>>>(wv, x, bv, vbf, CDIM);
  sq_kernel<<<dim3(BDIM * NDIM / 256), 256, 0, stream>>>(qT, sq);
  attn_mfma<<<dim3(NDIM / 64, BDIM), 512, 0, stream>>>(qT, vbf, sq, xr);
  gemm_wx<false, true,  false><<<dim3(NDIM / 64, CDIM / 64, BDIM), 256, 0, stream>>>(wt, xr, bt, out, CDIM);
  bnstats_kernel<<<dim3(CDIM), 256, 0, stream>>>(out, gamma, beta, scale, shift);
  final_kernel<<<dim3((BDIM * CDIM * NDIM) / (256 * 4)), 256, 0, stream>>>(x, scale, shift, out);
}

// Round 4
// 116.457 us; speedup vs baseline: 5.6882x; 1.5603x over previous
//
#include <hip/hip_runtime.h>
#include <math.h>

#define BDIM 8
#define CDIM 256
#define C4DIM 64
#define NDIM 2048
#define LOG2E_SQ 2.0813689810056077f
#define NEG_2LOG2E_SQ -4.1627379620112154f

typedef short bf16x8 __attribute__((ext_vector_type(8)));
typedef float f32x4 __attribute__((ext_vector_type(4)));

__device__ inline unsigned cvt_pk(float lo, float hi) {
  unsigned r;
  asm("v_cvt_pk_bf16_f32 %0, %1, %2" : "=v"(r) : "v"(lo), "v"(hi));
  return r;
}
__device__ inline float bflo(unsigned u) {
  u <<= 16; float f; __builtin_memcpy(&f, &u, 4); return f;
}
__device__ inline float bfhi(unsigned u) {
  u &= 0xffff0000u; float f; __builtin_memcpy(&f, &u, 4); return f;
}

// ---------------------------------------------------------------------------
// Cast the three weight matrices to bf16 (concatenated index space).
// wq: 64x256 (16384), wv: 256x256 (65536), wt: 256x256 (65536)
// ---------------------------------------------------------------------------
__global__ __launch_bounds__(256) void castw_kernel(const float* __restrict__ wq,
                                                    const float* __restrict__ wv,
                                                    const float* __restrict__ wt,
                                                    short* __restrict__ wqb,
                                                    short* __restrict__ wvb,
                                                    short* __restrict__ wtb) {
  const int idx = (blockIdx.x * 256 + threadIdx.x) * 4;
  const float* src; short* dst; int off;
  if (idx < 16384)       { src = wq; dst = wqb; off = idx; }
  else if (idx < 81920)  { src = wv; dst = wvb; off = idx - 16384; }
  else                   { src = wt; dst = wtb; off = idx - 81920; }
  float4 v = *(const float4*)&src[off];
  uint2 u = make_uint2(cvt_pk(v.x, v.y), cvt_pk(v.z, v.w));
  *(uint2*)&dst[off] = u;
}

// ---------------------------------------------------------------------------
// x[b][c][n] fp32 -> xT[b][n][c] bf16 (LDS-tiled transpose, 64x64 tiles)
// ---------------------------------------------------------------------------
__global__ __launch_bounds__(256) void castT_kernel(const float* __restrict__ x,
                                                    short* __restrict__ xT) {
  __shared__ float tile[64][65];
  const int b = blockIdx.z, c0 = blockIdx.y * 64, n0 = blockIdx.x * 64;
  const int t = threadIdx.x;
  const int cl = t >> 2, ng = (t & 3) * 16;
#pragma unroll
  for (int kk = 0; kk < 4; ++kk) {
    float4 v = *(const float4*)&x[((size_t)(b * CDIM + c0 + cl)) * NDIM + n0 + ng + kk * 4];
    tile[cl][ng + kk * 4 + 0] = v.x; tile[cl][ng + kk * 4 + 1] = v.y;
    tile[cl][ng + kk * 4 + 2] = v.z; tile[cl][ng + kk * 4 + 3] = v.w;
  }
  __syncthreads();
  const int nl = t >> 2, cg = (t & 3) * 16;
  unsigned u[8];
#pragma unroll
  for (int e = 0; e < 8; ++e)
    u[e] = cvt_pk(tile[cg + 2 * e][nl], tile[cg + 2 * e + 1][nl]);
  short* dst = &xT[((size_t)b * NDIM + n0 + nl) * CDIM + c0 + cg];
  *(uint4*)&dst[0] = make_uint4(u[0], u[1], u[2], u[3]);
  *(uint4*)&dst[8] = make_uint4(u[4], u[5], u[6], u[7]);
}

// ---------------------------------------------------------------------------
// q-GEMM (MFMA): q = wq * x -> qT[b][n][64] bf16, and sq2[b][n] =
// log2e^2 * sum_o q_bf16^2 (from the ROUNDED q, so attn diagonal d2 ~ 0).
// Block 4 waves, wave w: n-tile of 16 at n0+w*16; full o=64 per wave.
// ---------------------------------------------------------------------------
__global__ __launch_bounds__(256) void qgemm_kernel(const short* __restrict__ wqb,
                                                    const short* __restrict__ xT,
                                                    short* __restrict__ qT,
                                                    float* __restrict__ sq2) {
  const int b = blockIdx.y, n0 = blockIdx.x * 64;
  const int t = threadIdx.x, w = t >> 6, l = t & 63, il = l & 15, g = l >> 4;
  const int nw = n0 + w * 16;
  f32x4 acc[4] = {};
#pragma unroll
  for (int ks = 0; ks < 8; ++ks) {
    const int k0 = ks * 32;
    bf16x8 bx = *(const bf16x8*)&xT[((size_t)b * NDIM + nw + il) * CDIM + k0 + g * 8];
#pragma unroll
    for (int ot = 0; ot < 4; ++ot) {
      bf16x8 aw = *(const bf16x8*)&wqb[(size_t)(ot * 16 + il) * CDIM + k0 + g * 8];
      acc[ot] = __builtin_amdgcn_mfma_f32_16x16x32_bf16(aw, bx, acc[ot], 0, 0, 0);
    }
  }
  // D: lane(il,g) reg r = q[o = ot*16+g*4+r][n = nw+il]
  float sqs = 0.f;
#pragma unroll
  for (int ot = 0; ot < 4; ++ot) {
    unsigned u0 = cvt_pk(acc[ot][0], acc[ot][1]);
    unsigned u1 = cvt_pk(acc[ot][2], acc[ot][3]);
    *(uint2*)&qT[((size_t)b * NDIM + nw + il) * C4DIM + ot * 16 + g * 4] = make_uint2(u0, u1);
    float f0 = bflo(u0), f1 = bfhi(u0), f2 = bflo(u1), f3 = bfhi(u1);
    sqs += f0 * f0 + f1 * f1 + f2 * f2 + f3 * f3;
  }
  sqs += __shfl_xor(sqs, 16, 64);
  sqs += __shfl_xor(sqs, 32, 64);
  if (l < 16) sq2[(size_t)b * NDIM + nw + l] = sqs * LOG2E_SQ;
}

// ---------------------------------------------------------------------------
// v / t GEMM (MFMA): OUT[b][c][n] = W(256x256) * X[b] + bias
// A = Xt rows (n), B = W cols (c): D lane(il,g) r = out[n=...g*4+r][c=...il]
// F32OUT: fp32 to d_out + fused BN partial sums (atomics); else bf16 out.
// Block 4 waves (2n x 2c), tile 128n x 128c. grid (16, 2, 8).
// ---------------------------------------------------------------------------
template<bool F32OUT>
__global__ __launch_bounds__(256) void vt_gemm(const short* __restrict__ Wb,
                                               const short* __restrict__ Xt,
                                               const float* __restrict__ bias,
                                               void* __restrict__ OUTP,
                                               float* __restrict__ bnsum,
                                               float* __restrict__ bnss) {
  const int b = blockIdx.z, n0 = blockIdx.x * 128, c0 = blockIdx.y * 128;
  const int t = threadIdx.x, w = t >> 6, l = t & 63, il = l & 15, g = l >> 4;
  const int wn = w & 1, wc = w >> 1;
  const size_t arow = (size_t)b * NDIM + n0 + wn * 64;
  const int ccol = c0 + wc * 64;
  f32x4 acc[4][4] = {};
#pragma unroll
  for (int ks = 0; ks < 8; ++ks) {
    const int k0 = ks * 32;
    bf16x8 af[4], bf[4];
#pragma unroll
    for (int nt = 0; nt < 4; ++nt)
      af[nt] = *(const bf16x8*)&Xt[(arow + nt * 16 + il) * CDIM + k0 + g * 8];
#pragma unroll
    for (int ct = 0; ct < 4; ++ct)
      bf[ct] = *(const bf16x8*)&Wb[(size_t)(ccol + ct * 16 + il) * CDIM + k0 + g * 8];
#pragma unroll
    for (int nt = 0; nt < 4; ++nt)
#pragma unroll
      for (int ct = 0; ct < 4; ++ct)
        acc[nt][ct] = __builtin_amdgcn_mfma_f32_16x16x32_bf16(af[nt], bf[ct], acc[nt][ct], 0, 0, 0);
  }
#pragma unroll
  for (int ct = 0; ct < 4; ++ct) {
    const int c = ccol + ct * 16 + il;
    const float bs = bias[c];
    float s = 0.f, ss = 0.f;
#pragma unroll
    for (int nt = 0; nt < 4; ++nt) {
      const int n = n0 + wn * 64 + nt * 16 + g * 4;
      float y0 = acc[nt][ct][0] + bs, y1 = acc[nt][ct][1] + bs;
      float y2 = acc[nt][ct][2] + bs, y3 = acc[nt][ct][3] + bs;
      if (F32OUT) {
        *(float4*)&((float*)OUTP)[((size_t)(b * CDIM + c)) * NDIM + n] =
            make_float4(y0, y1, y2, y3);
        s += y0 + y1 + y2 + y3;
        ss += y0 * y0 + y1 * y1 + y2 * y2 + y3 * y3;
      } else {
        *(uint2*)&((short*)OUTP)[((size_t)(b * CDIM + c)) * NDIM + n] =
            make_uint2(cvt_pk(y0, y1), cvt_pk(y2, y3));
      }
    }
    if (F32OUT) {
      s += __shfl_xor(s, 16, 64);   s += __shfl_xor(s, 32, 64);
      ss += __shfl_xor(ss, 16, 64); ss += __shfl_xor(ss, 32, 64);
      if (l < 16) { atomicAdd(&bnsum[c], s); atomicAdd(&bnss[c], ss); }
    }
  }
}

// ---------------------------------------------------------------------------
// MFMA L2 attention v3.  Block = (b, 64 queries), 8 waves (512 thr).
// Wave w: isub=w&3 (16 i's), chalf=w>>2 (8 c-tiles + gram half h=chalf).
// Per 32-j step: gram OWN HALF only (dedup) -> softmax (exp2-folded) ->
// cvt_pk -> w tile in LDS [isub][16i][40j] -> barrier -> PV B-frag via one
// ds_read_b128 -> 8 PV MFMA -> stage next (dbuf) -> barrier.
// Output written directly as xrT[b][n][c] bf16 for the t-GEMM.
// ---------------------------------------------------------------------------
__global__ __launch_bounds__(512) void attn_mfma(const short* __restrict__ qT,
                                                 const short* __restrict__ Vb16,
                                                 const float* __restrict__ sq2,
                                                 short* __restrict__ xrT) {
  __shared__ __align__(16) short vj[2][256 * 32];
  __shared__ __align__(16) short qj[2][32 * 64];
  __shared__ __align__(16) short wlds[4][16][40];  // [isub][i][j], 80B rows
  __shared__ float sums[8][16];

  const int b  = blockIdx.y;
  const int i0 = blockIdx.x * 64;
  const int t  = threadIdx.x;
  const int w  = t >> 6, l = t & 63;
  const int il = l & 15, g = l >> 4;
  const int isub = w & 3, chalf = w >> 2;

  const short* qTb = qT + (size_t)b * NDIM * C4DIM;
  const short* Vbb = Vb16 + (size_t)b * CDIM * NDIM;
  const float* sqb = sq2 + (size_t)b * NDIM;

  const int iglob = i0 + isub * 16 + il;
  const bf16x8 bq0 = *(const bf16x8*)&qTb[(size_t)iglob * C4DIM + g * 8];
  const bf16x8 bq1 = *(const bf16x8*)&qTb[(size_t)iglob * C4DIM + 32 + g * 8];
  const float sqi = sqb[iglob];

  const int vc0 = t >> 2, vs0 = t & 3;
  const int vc1 = 128 + (t >> 2);
  const int vd0 = vc0 * 32 + ((vs0 ^ ((vc0 >> 1) & 3)) << 3);
  const int vd1 = vc1 * 32 + ((vs0 ^ ((vc1 >> 1) & 3)) << 3);
  const int qrow = t >> 3, qslot = t & 7;
  const int qd = qrow * 64 + ((qslot ^ (qrow & 7)) << 3);

  f32x4 acc[8];
#pragma unroll
  for (int k = 0; k < 8; ++k) acc[k] = {0.f, 0.f, 0.f, 0.f};
  float sumw = 0.f;

  f32x4 sqc;
  { // prologue: stage step 0
    bf16x8 vr0 = *(const bf16x8*)&Vbb[(size_t)vc0 * NDIM + vs0 * 8];
    bf16x8 vr1 = *(const bf16x8*)&Vbb[(size_t)vc1 * NDIM + vs0 * 8];
    *(bf16x8*)&vj[0][vd0] = vr0;
    *(bf16x8*)&vj[0][vd1] = vr1;
    if (w < 4) {
      bf16x8 qr = *(const bf16x8*)&qTb[(size_t)qrow * C4DIM + qslot * 8];
      *(bf16x8*)&qj[0][qd] = qr;
    }
    sqc = *(const f32x4*)&sqb[chalf * 16 + g * 4];
  }
  __syncthreads();

  const int NT = NDIM / 32;
  for (int jt = 0; jt < NT; ++jt) {
    const int p = jt & 1;
    const short* vbuf = &vj[p][0];
    const short* qbuf = &qj[p][0];
    short* vbufN = &vj[p ^ 1][0];
    short* qbufN = &qj[p ^ 1][0];
    const bool has_next = (jt + 1 < NT);
    const int j0n = jt * 32 + 32;

    bf16x8 vr0 = {}, vr1 = {}, qr = {};
    f32x4 sqn = {};
    if (has_next) {
      vr0 = *(const bf16x8*)&Vbb[(size_t)vc0 * NDIM + j0n + vs0 * 8];
      vr1 = *(const bf16x8*)&Vbb[(size_t)vc1 * NDIM + j0n + vs0 * 8];
      if (w < 4) qr = *(const bf16x8*)&qTb[(size_t)(j0n + qrow) * C4DIM + qslot * 8];
      sqn = *(const f32x4*)&sqb[j0n + chalf * 16 + g * 4];
    }

    // ---- gram own half: w[j = chalf*16 + g*4+r][i = il] ----
    {
      const int row = chalf * 16 + il;
      bf16x8 aJ0 = *(const bf16x8*)&qbuf[row * 64 + ((g ^ (il & 7)) << 3)];
      bf16x8 aJ1 = *(const bf16x8*)&qbuf[row * 64 + (((4 + g) ^ (il & 7)) << 3)];
      f32x4 s = {0.f, 0.f, 0.f, 0.f};
      s = __builtin_amdgcn_mfma_f32_16x16x32_bf16(aJ0, bq0, s, 0, 0, 0);
      s = __builtin_amdgcn_mfma_f32_16x16x32_bf16(aJ1, bq1, s, 0, 0, 0);
      float wv[4];
#pragma unroll
      for (int r = 0; r < 4; ++r) {
        float e = fmaxf(fmaf(NEG_2LOG2E_SQ, s[r], sqi + sqc[r]), 0.f);
        wv[r] = __builtin_amdgcn_exp2f(-__builtin_amdgcn_sqrtf(e));
        sumw += wv[r];
      }
      *(uint2*)&wlds[isub][il][chalf * 16 + g * 4] =
          make_uint2(cvt_pk(wv[0], wv[1]), cvt_pk(wv[2], wv[3]));
    }
    __syncthreads();  // w tile complete

    // ---- PV: B-frag = w[j = g*8+e][i = il] straight from the tile ----
    const bf16x8 bw = *(const bf16x8*)&wlds[isub][il][g * 8];
#pragma unroll
    for (int ctl = 0; ctl < 8; ++ctl) {
      const int c = (chalf * 8 + ctl) * 16 + il;
      bf16x8 aV = *(const bf16x8*)&vbuf[c * 32 + ((g ^ ((il >> 1) & 3)) << 3)];
      acc[ctl] = __builtin_amdgcn_mfma_f32_16x16x32_bf16(aV, bw, acc[ctl], 0, 0, 0);
    }

    if (has_next) {
      *(bf16x8*)&vbufN[vd0] = vr0;
      *(bf16x8*)&vbufN[vd1] = vr1;
      if (w < 4) *(bf16x8*)&qbufN[qd] = qr;
      sqc = sqn;
    }
    __syncthreads();  // staging done + w reads done
  }

  // ---- cross-half sum exchange + normalize + bf16 transposed write ----
  sumw += __shfl_xor(sumw, 16, 64);
  sumw += __shfl_xor(sumw, 32, 64);
  if (l < 16) sums[w][l] = sumw;
  __syncthreads();
  const float inv = 1.f / (sums[w][il] + sums[w ^ 4][il]);
#pragma unroll
  for (int ctl = 0; ctl < 8; ++ctl) {
    float y0 = acc[ctl][0] * inv, y1 = acc[ctl][1] * inv;
    float y2 = acc[ctl][2] * inv, y3 = acc[ctl][3] * inv;
    *(uint2*)&xrT[((size_t)b * NDIM + iglob) * CDIM + (chalf * 8 + ctl) * 16 + g * 4] =
        make_uint2(cvt_pk(y0, y1), cvt_pk(y2, y3));
  }
}

// ---------------------------------------------------------------------------
// BN finalize: scale/shift from the atomically-accumulated sums.
// ---------------------------------------------------------------------------
__global__ __launch_bounds__(256) void bn_small(const float* __restrict__ bnsum,
                                                const float* __restrict__ bnss,
                                                const float* __restrict__ gamma,
                                                const float* __restrict__ beta,
                                                float* __restrict__ scale,
                                                float* __restrict__ shift) {
  const int c = threadIdx.x;
  const float cnt = (float)(BDIM * NDIM);
  const float mean = bnsum[c] / cnt;
  const float var = fmaxf(bnss[c] / cnt - mean * mean, 0.f);
  const float sc = gamma[c] * rsqrtf(var + 1e-5f);
  scale[c] = sc;
  shift[c] = beta[c] - mean * sc;
}

__global__ __launch_bounds__(256) void final_kernel(const float* __restrict__ x,
                                                    const float* __restrict__ scale,
                                                    const float* __restrict__ shift,
                                                    float* __restrict__ out) {
  const size_t idx = ((size_t)blockIdx.x * 256 + threadIdx.x) << 2;
  const int c = (int)((idx >> 11) & 255);
  float4 xv = *(const float4*)&x[idx];
  float4 tv = *(const float4*)&out[idx];
  const float sc = scale[c], sh = shift[c];
  float4 r;
  r.x = xv.x + fmaxf(tv.x * sc + sh, 0.f);
  r.y = xv.y + fmaxf(tv.y * sc + sh, 0.f);
  r.z = xv.z + fmaxf(tv.z * sc + sh, 0.f);
  r.w = xv.w + fmaxf(tv.w * sc + sh, 0.f);
  *(float4*)&out[idx] = r;
}

extern "C" void kernel_launch(void* const* d_in, const int* in_sizes, int n_in,
                              void* d_out, int out_size, void* d_ws, size_t ws_size,
                              hipStream_t stream) {
  const float* x     = (const float*)d_in[0];
  const float* wq    = (const float*)d_in[1];
  const float* wv    = (const float*)d_in[2];
  const float* bv    = (const float*)d_in[3];
  const float* wt    = (const float*)d_in[4];
  const float* bt    = (const float*)d_in[5];
  const float* gamma = (const float*)d_in[6];
  const float* beta  = (const float*)d_in[7];
  float* out = (float*)d_out;
  char* ws = (char*)d_ws;

  short* xbT   = (short*)(ws);                       // [B][N][C] bf16  8.4 MB
  short* wqb   = (short*)(ws + ((size_t)9  << 20));  // 32 KB
  short* wvb   = (short*)(ws + ((size_t)9  << 20) + (256 << 10));
  short* wtb   = (short*)(ws + ((size_t)9  << 20) + (512 << 10));
  short* qT    = (short*)(ws + ((size_t)10 << 20));  // [B][N][64] bf16  2 MB
  float* sq2   = (float*)(ws + ((size_t)12 << 20));  // [B][N] f32 (x log2e^2)
  short* vbf   = (short*)(ws + ((size_t)13 << 20));  // [B][C][N] bf16  8.4 MB
  short* xrT   = (short*)(ws + ((size_t)22 << 20));  // [B][N][C] bf16  8.4 MB
  float* bnsum = (float*)(ws + ((size_t)31 << 20));  // 256
  float* bnss  = bnsum + 256;
  float* scale = bnsum + 512;
  float* shift = bnsum + 768;

  castw_kernel<<<dim3(144), 256, 0, stream>>>(wq, wv, wt, wqb, wvb, wtb);
  castT_kernel<<<dim3(NDIM / 64, CDIM / 64, BDIM), 256, 0, stream>>>(x, xbT);
  qgemm_kernel<<<dim3(NDIM / 64, BDIM), 256, 0, stream>>>(wqb, xbT, qT, sq2);
  vt_gemm<false><<<dim3(NDIM / 128, CDIM / 128, BDIM), 256, 0, stream>>>(
      wvb, xbT, bv, vbf, nullptr, nullptr);
  attn_mfma<<<dim3(NDIM / 64, BDIM), 512, 0, stream>>>(qT, vbf, sq2, xrT);
  hipMemsetAsync((void*)bnsum, 0, 2048, stream);
  vt_gemm<true><<<dim3(NDIM / 128, CDIM / 128, BDIM), 256, 0, stream>>>(
      wtb, xrT, bt, out, bnsum, bnss);
  bn_small<<<dim3(1), 256, 0, stream>>>(bnsum, bnss, gamma, beta, scale, shift);
  final_kernel<<<dim3((BDIM * CDIM * NDIM) / (256 * 4)), 256, 0, stream>>>(x, scale, shift, out);
}

// Round 5
// 103.320 us; speedup vs baseline: 6.4115x; 1.1272x over previous
//
#include <hip/hip_runtime.h>
#include <math.h>

#define BDIM 8
#define CDIM 256
#define C4DIM 64
#define NDIM 2048
#define LOG2E_SQ 2.0813689810056077f
#define NEG_2LOG2E_SQ -4.1627379620112154f

typedef short bf16x8 __attribute__((ext_vector_type(8)));
typedef float f32x4 __attribute__((ext_vector_type(4)));

__device__ inline unsigned cvt_pk(float lo, float hi) {
  unsigned r;
  asm("v_cvt_pk_bf16_f32 %0, %1, %2" : "=v"(r) : "v"(lo), "v"(hi));
  return r;
}
__device__ inline float bflo(unsigned u) {
  u <<= 16; float f; __builtin_memcpy(&f, &u, 4); return f;
}
__device__ inline float bfhi(unsigned u) {
  u &= 0xffff0000u; float f; __builtin_memcpy(&f, &u, 4); return f;
}

// ---------------------------------------------------------------------------
// prep: [0,1024) castT x->xT bf16; [1024,1168) cast weights; 1168 zero bn sums
// ---------------------------------------------------------------------------
__global__ __launch_bounds__(256) void prep_kernel(const float* __restrict__ x,
                                                   const float* __restrict__ wq,
                                                   const float* __restrict__ wv,
                                                   const float* __restrict__ wt,
                                                   short* __restrict__ xT,
                                                   short* __restrict__ wqb,
                                                   short* __restrict__ wvb,
                                                   short* __restrict__ wtb,
                                                   float* __restrict__ bnsum) {
  __shared__ float tile[64][65];
  const int fb = blockIdx.x, t = threadIdx.x;
  if (fb < 1024) {
    const int b = fb >> 7, c0 = ((fb >> 5) & 3) * 64, n0 = (fb & 31) * 64;
    const int cl = t >> 2, ng = (t & 3) * 16;
#pragma unroll
    for (int kk = 0; kk < 4; ++kk) {
      float4 v = *(const float4*)&x[((size_t)(b * CDIM + c0 + cl)) * NDIM + n0 + ng + kk * 4];
      tile[cl][ng + kk * 4 + 0] = v.x; tile[cl][ng + kk * 4 + 1] = v.y;
      tile[cl][ng + kk * 4 + 2] = v.z; tile[cl][ng + kk * 4 + 3] = v.w;
    }
    __syncthreads();
    const int nl = t >> 2, cg = (t & 3) * 16;
    unsigned u[8];
#pragma unroll
    for (int e = 0; e < 8; ++e)
      u[e] = cvt_pk(tile[cg + 2 * e][nl], tile[cg + 2 * e + 1][nl]);
    short* dst = &xT[((size_t)b * NDIM + n0 + nl) * CDIM + c0 + cg];
    *(uint4*)&dst[0] = make_uint4(u[0], u[1], u[2], u[3]);
    *(uint4*)&dst[8] = make_uint4(u[4], u[5], u[6], u[7]);
  } else if (fb < 1168) {
    const int idx = ((fb - 1024) * 256 + t) * 4;
    const float* src; short* dst; int off;
    if (idx < 16384)      { src = wq; dst = wqb; off = idx; }
    else if (idx < 81920) { src = wv; dst = wvb; off = idx - 16384; }
    else                  { src = wt; dst = wtb; off = idx - 81920; }
    float4 v = *(const float4*)&src[off];
    *(uint2*)&dst[off] = make_uint2(cvt_pk(v.x, v.y), cvt_pk(v.z, v.w));
  } else {
    bnsum[t] = 0.f; bnsum[256 + t] = 0.f;
  }
}

// ---------------------------------------------------------------------------
// 128x128 MFMA GEMM body: OUT[b][c][n] (bf16) = W * X[b] + bias.
// STATS: fused BN partial sums via per-channel atomics.
// ---------------------------------------------------------------------------
template<bool STATS>
__device__ __forceinline__ void gemm128(const short* __restrict__ Wb,
                                        const short* __restrict__ Xt,
                                        const float* __restrict__ bias,
                                        short* __restrict__ OUT,
                                        float* __restrict__ bnsum,
                                        float* __restrict__ bnss,
                                        int b, int n0, int c0, int t) {
  const int w = t >> 6, l = t & 63, il = l & 15, g = l >> 4;
  const int wn = w & 1, wc = w >> 1;
  const size_t arow = (size_t)b * NDIM + n0 + wn * 64;
  const int ccol = c0 + wc * 64;
  f32x4 acc[4][4] = {};
#pragma unroll
  for (int ks = 0; ks < 8; ++ks) {
    const int k0 = ks * 32;
    bf16x8 af[4], bfr[4];
#pragma unroll
    for (int nt = 0; nt < 4; ++nt)
      af[nt] = *(const bf16x8*)&Xt[(arow + nt * 16 + il) * CDIM + k0 + g * 8];
#pragma unroll
    for (int ct = 0; ct < 4; ++ct)
      bfr[ct] = *(const bf16x8*)&Wb[(size_t)(ccol + ct * 16 + il) * CDIM + k0 + g * 8];
#pragma unroll
    for (int nt = 0; nt < 4; ++nt)
#pragma unroll
      for (int ct = 0; ct < 4; ++ct)
        acc[nt][ct] = __builtin_amdgcn_mfma_f32_16x16x32_bf16(af[nt], bfr[ct], acc[nt][ct], 0, 0, 0);
  }
#pragma unroll
  for (int ct = 0; ct < 4; ++ct) {
    const int c = ccol + ct * 16 + il;
    const float bs = bias[c];
    float s = 0.f, ss = 0.f;
#pragma unroll
    for (int nt = 0; nt < 4; ++nt) {
      const int n = n0 + wn * 64 + nt * 16 + g * 4;
      float y0 = acc[nt][ct][0] + bs, y1 = acc[nt][ct][1] + bs;
      float y2 = acc[nt][ct][2] + bs, y3 = acc[nt][ct][3] + bs;
      *(uint2*)&OUT[((size_t)(b * CDIM + c)) * NDIM + n] =
          make_uint2(cvt_pk(y0, y1), cvt_pk(y2, y3));
      if (STATS) {
        s += y0 + y1 + y2 + y3;
        ss += y0 * y0 + y1 * y1 + y2 * y2 + y3 * y3;
      }
    }
    if (STATS) {
      s += __shfl_xor(s, 16, 64);   s += __shfl_xor(s, 32, 64);
      ss += __shfl_xor(ss, 16, 64); ss += __shfl_xor(ss, 32, 64);
      if (l < 16) { atomicAdd(&bnsum[c], s); atomicAdd(&bnss[c], ss); }
    }
  }
}

// ---------------------------------------------------------------------------
// qv_gemm: [0,256) v-gemm (128x128 tiles); [256,512) q-gemm + sq2 fusion.
// ---------------------------------------------------------------------------
__global__ __launch_bounds__(256) void qv_gemm(const short* __restrict__ wqb,
                                               const short* __restrict__ wvb,
                                               const short* __restrict__ xT,
                                               const float* __restrict__ bv,
                                               short* __restrict__ qT,
                                               float* __restrict__ sq2,
                                               short* __restrict__ vbf) {
  const int fb = blockIdx.x, t = threadIdx.x;
  if (fb < 256) {
    const int b = fb >> 5, c0 = ((fb >> 4) & 1) * 128, n0 = (fb & 15) * 128;
    gemm128<false>(wvb, xT, bv, vbf, nullptr, nullptr, b, n0, c0, t);
  } else {
    const int f = fb - 256;
    const int b = f >> 5, n0 = (f & 31) * 64;
    const int w = t >> 6, l = t & 63, il = l & 15, g = l >> 4;
    const int nw = n0 + w * 16;
    f32x4 acc[4] = {};
#pragma unroll
    for (int ks = 0; ks < 8; ++ks) {
      const int k0 = ks * 32;
      bf16x8 bx = *(const bf16x8*)&xT[((size_t)b * NDIM + nw + il) * CDIM + k0 + g * 8];
#pragma unroll
      for (int ot = 0; ot < 4; ++ot) {
        bf16x8 aw = *(const bf16x8*)&wqb[(size_t)(ot * 16 + il) * CDIM + k0 + g * 8];
        acc[ot] = __builtin_amdgcn_mfma_f32_16x16x32_bf16(aw, bx, acc[ot], 0, 0, 0);
      }
    }
    float sqs = 0.f;
#pragma unroll
    for (int ot = 0; ot < 4; ++ot) {
      unsigned u0 = cvt_pk(acc[ot][0], acc[ot][1]);
      unsigned u1 = cvt_pk(acc[ot][2], acc[ot][3]);
      *(uint2*)&qT[((size_t)b * NDIM + nw + il) * C4DIM + ot * 16 + g * 4] = make_uint2(u0, u1);
      float f0 = bflo(u0), f1 = bfhi(u0), f2 = bflo(u1), f3 = bfhi(u1);
      sqs += f0 * f0 + f1 * f1 + f2 * f2 + f3 * f3;
    }
    sqs += __shfl_xor(sqs, 16, 64);
    sqs += __shfl_xor(sqs, 32, 64);
    if (l < 16) sq2[(size_t)b * NDIM + nw + l] = sqs * LOG2E_SQ;
  }
}

// ---------------------------------------------------------------------------
// MFMA L2 attention v4.  Grid 512 (XCD-swizzled: each XCD pins one batch b).
// Block = (b, 64 queries, c-half 128ch), 4 waves (256 thr); wave = i-subtile.
// Per 32-j step (single barrier):
//   gram both j-halves (4 MFMA) -> softmax 8 vals (exp2-folded) ->
//   w-tile intra-WAVE LDS write/read (no barrier) -> 8 PV MFMA ->
//   stage next V/q (dbuf) -> one __syncthreads.
// Weights<=1 (diagonal d2~0 from bf16-consistent sq), so partials are linear;
// each wave owns its (isub, chalf) output fully: shfl-reduce sumw, normalize.
// ---------------------------------------------------------------------------
__global__ __launch_bounds__(256) void attn_mfma(const short* __restrict__ qT,
                                                 const short* __restrict__ Vb16,
                                                 const float* __restrict__ sq2,
                                                 short* __restrict__ xrT) {
  __shared__ __align__(16) short vj[2][128 * 32];   // own c-half, 8 KB each
  __shared__ __align__(16) short qj[2][32 * 64];    // 4 KB each
  __shared__ __align__(16) short wlds[4][16][40];   // per-wave w tiles

  const int bid = blockIdx.x;
  const int swz = (bid & 7) * 64 + (bid >> 3);      // XCD-contiguous
  const int i0    = (swz & 31) * 64;
  const int chalf = (swz >> 5) & 1;
  const int b     = swz >> 6;

  const int t = threadIdx.x;
  const int w = t >> 6, l = t & 63, il = l & 15, g = l >> 4;

  const short* qTb = qT + (size_t)b * NDIM * C4DIM;
  const short* Vbb = Vb16 + ((size_t)b * CDIM + chalf * 128) * NDIM;
  const float* sqb = sq2 + (size_t)b * NDIM;

  const int iglob = i0 + w * 16 + il;
  const bf16x8 bq0 = *(const bf16x8*)&qTb[(size_t)iglob * C4DIM + g * 8];
  const bf16x8 bq1 = *(const bf16x8*)&qTb[(size_t)iglob * C4DIM + 32 + g * 8];
  const float sqi = sqb[iglob];

  // staging maps: 2 V chunks (local rows vcb, vcb+64), 1 q chunk per thread
  const int vcb = t >> 2, vs = t & 3;
  const int vd0 = vcb * 32 + ((vs ^ ((vcb >> 1) & 3)) << 3);
  const int vd1 = vd0 + 64 * 32;
  const int qrow = t >> 3, qslot = t & 7;
  const int qd = qrow * 64 + ((qslot ^ (qrow & 7)) << 3);

  f32x4 acc[8];
#pragma unroll
  for (int k = 0; k < 8; ++k) acc[k] = {0.f, 0.f, 0.f, 0.f};
  float sumw = 0.f;

  f32x4 sqc0, sqc1;
  { // prologue: stage step 0
    bf16x8 vr0 = *(const bf16x8*)&Vbb[(size_t)vcb * NDIM + vs * 8];
    bf16x8 vr1 = *(const bf16x8*)&Vbb[(size_t)(vcb + 64) * NDIM + vs * 8];
    *(bf16x8*)&vj[0][vd0] = vr0;
    *(bf16x8*)&vj[0][vd1] = vr1;
    bf16x8 qr = *(const bf16x8*)&qTb[(size_t)qrow * C4DIM + qslot * 8];
    *(bf16x8*)&qj[0][qd] = qr;
    sqc0 = *(const f32x4*)&sqb[g * 4];
    sqc1 = *(const f32x4*)&sqb[16 + g * 4];
  }
  __syncthreads();

  const int NT = NDIM / 32;
  for (int jt = 0; jt < NT; ++jt) {
    const int p = jt & 1;
    const short* vbuf = &vj[p][0];
    const short* qbuf = &qj[p][0];
    short* vbufN = &vj[p ^ 1][0];
    short* qbufN = &qj[p ^ 1][0];
    const bool has_next = (jt + 1 < NT);
    const int j0n = jt * 32 + 32;

    bf16x8 vr0 = {}, vr1 = {}, qr = {};
    f32x4 sqn0 = {}, sqn1 = {};
    if (has_next) {
      vr0 = *(const bf16x8*)&Vbb[(size_t)vcb * NDIM + j0n + vs * 8];
      vr1 = *(const bf16x8*)&Vbb[(size_t)(vcb + 64) * NDIM + j0n + vs * 8];
      qr  = *(const bf16x8*)&qTb[(size_t)(j0n + qrow) * C4DIM + qslot * 8];
      sqn0 = *(const f32x4*)&sqb[j0n + g * 4];
      sqn1 = *(const f32x4*)&sqb[j0n + 16 + g * 4];
    }

    // ---- gram both halves: w[j = h*16 + g*4 + r][i = il] ----
#pragma unroll
    for (int h = 0; h < 2; ++h) {
      const int row = h * 16 + il;
      bf16x8 aJ0 = *(const bf16x8*)&qbuf[row * 64 + ((g ^ (il & 7)) << 3)];
      bf16x8 aJ1 = *(const bf16x8*)&qbuf[row * 64 + (((4 + g) ^ (il & 7)) << 3)];
      f32x4 s = {0.f, 0.f, 0.f, 0.f};
      s = __builtin_amdgcn_mfma_f32_16x16x32_bf16(aJ0, bq0, s, 0, 0, 0);
      s = __builtin_amdgcn_mfma_f32_16x16x32_bf16(aJ1, bq1, s, 0, 0, 0);
      const f32x4 sqh = h ? sqc1 : sqc0;
      float wv[4];
#pragma unroll
      for (int r = 0; r < 4; ++r) {
        float e = fmaxf(fmaf(NEG_2LOG2E_SQ, s[r], sqi + sqh[r]), 0.f);
        wv[r] = __builtin_amdgcn_exp2f(-__builtin_amdgcn_sqrtf(e));
        sumw += wv[r];
      }
      *(uint2*)&wlds[w][il][h * 16 + g * 4] =
          make_uint2(cvt_pk(wv[0], wv[1]), cvt_pk(wv[2], wv[3]));
    }

    // ---- intra-wave exchange (no barrier; compiler inserts lgkmcnt) ----
    const bf16x8 bw = *(const bf16x8*)&wlds[w][il][g * 8];

    // ---- PV: 8 c-tiles (this block's c-half) ----
#pragma unroll
    for (int ctl = 0; ctl < 8; ++ctl) {
      const int lr = ctl * 16 + il;
      bf16x8 aV = *(const bf16x8*)&vbuf[lr * 32 + ((g ^ ((il >> 1) & 3)) << 3)];
      acc[ctl] = __builtin_amdgcn_mfma_f32_16x16x32_bf16(aV, bw, acc[ctl], 0, 0, 0);
    }

    if (has_next) {
      *(bf16x8*)&vbufN[vd0] = vr0;
      *(bf16x8*)&vbufN[vd1] = vr1;
      *(bf16x8*)&qbufN[qd] = qr;
      sqc0 = sqn0; sqc1 = sqn1;
    }
    __syncthreads();
  }

  // ---- normalize + bf16 transposed write ----
  sumw += __shfl_xor(sumw, 16, 64);
  sumw += __shfl_xor(sumw, 32, 64);
  const float inv = 1.f / sumw;
#pragma unroll
  for (int ctl = 0; ctl < 8; ++ctl) {
    float y0 = acc[ctl][0] * inv, y1 = acc[ctl][1] * inv;
    float y2 = acc[ctl][2] * inv, y3 = acc[ctl][3] * inv;
    *(uint2*)&xrT[((size_t)b * NDIM + iglob) * CDIM + chalf * 128 + ctl * 16 + g * 4] =
        make_uint2(cvt_pk(y0, y1), cvt_pk(y2, y3));
  }
}

// ---------------------------------------------------------------------------
// t-gemm: t = wt*x_r + bt (bf16 out) + fused BN partial sums.
// ---------------------------------------------------------------------------
__global__ __launch_bounds__(256) void t_gemm(const short* __restrict__ wtb,
                                              const short* __restrict__ xrT,
                                              const float* __restrict__ bt,
                                              short* __restrict__ tbf,
                                              float* __restrict__ bnsum,
                                              float* __restrict__ bnss) {
  gemm128<true>(wtb, xrT, bt, tbf, bnsum, bnss,
                blockIdx.z, blockIdx.x * 128, blockIdx.y * 128, threadIdx.x);
}

// ---------------------------------------------------------------------------
// final: BN finalize (inline from sums) + out = x + relu(bn(t))
// ---------------------------------------------------------------------------
__global__ __launch_bounds__(256) void final_kernel(const float* __restrict__ x,
                                                    const short* __restrict__ tbf,
                                                    const float* __restrict__ bnsum,
                                                    const float* __restrict__ bnss,
                                                    const float* __restrict__ gamma,
                                                    const float* __restrict__ beta,
                                                    float* __restrict__ out) {
  const size_t idx = ((size_t)blockIdx.x * 256 + threadIdx.x) << 2;
  const int c = (int)((idx >> 11) & 255);
  const float cnt = (float)(BDIM * NDIM);
  const float mean = bnsum[c] / cnt;
  const float var = fmaxf(bnss[c] / cnt - mean * mean, 0.f);
  const float sc = gamma[c] * rsqrtf(var + 1e-5f);
  const float sh = beta[c] - mean * sc;
  float4 xv = *(const float4*)&x[idx];
  uint2 tu = *(const uint2*)&tbf[idx];
  const float t0 = bflo(tu.x), t1 = bfhi(tu.x), t2 = bflo(tu.y), t3 = bfhi(tu.y);
  float4 r;
  r.x = xv.x + fmaxf(t0 * sc + sh, 0.f);
  r.y = xv.y + fmaxf(t1 * sc + sh, 0.f);
  r.z = xv.z + fmaxf(t2 * sc + sh, 0.f);
  r.w = xv.w + fmaxf(t3 * sc + sh, 0.f);
  *(float4*)&out[idx] = r;
}

extern "C" void kernel_launch(void* const* d_in, const int* in_sizes, int n_in,
                              void* d_out, int out_size, void* d_ws, size_t ws_size,
                              hipStream_t stream) {
  const float* x     = (const float*)d_in[0];
  const float* wq    = (const float*)d_in[1];
  const float* wv    = (const float*)d_in[2];
  const float* bv    = (const float*)d_in[3];
  const float* wt    = (const float*)d_in[4];
  const float* bt    = (const float*)d_in[5];
  const float* gamma = (const float*)d_in[6];
  const float* beta  = (const float*)d_in[7];
  float* out = (float*)d_out;
  char* ws = (char*)d_ws;

  short* xbT   = (short*)(ws);                       // [B][N][C] bf16  8 MB
  short* wqb   = (short*)(ws + ((size_t)9  << 20));  // 32 KB
  short* wvb   = (short*)(ws + ((size_t)9  << 20) + (256 << 10));
  short* wtb   = (short*)(ws + ((size_t)9  << 20) + (512 << 10));
  short* qT    = (short*)(ws + ((size_t)10 << 20));  // [B][N][64] bf16 2 MB
  float* sq2   = (float*)(ws + ((size_t)12 << 20));  // [B][N] f32
  short* vbf   = (short*)(ws + ((size_t)13 << 20));  // [B][C][N] bf16 8 MB
  short* xrT   = (short*)(ws + ((size_t)22 << 20));  // [B][N][C] bf16 8 MB
  short* tbf   = vbf;                                // reuse (v dead after attn)
  float* bnsum = (float*)(ws + ((size_t)31 << 20));  // 256 + 256
  float* bnss  = bnsum + 256;

  prep_kernel<<<dim3(1169), 256, 0, stream>>>(x, wq, wv, wt, xbT, wqb, wvb, wtb, bnsum);
  qv_gemm<<<dim3(512), 256, 0, stream>>>(wqb, wvb, xbT, bv, qT, sq2, vbf);
  attn_mfma<<<dim3(512), 256, 0, stream>>>(qT, vbf, sq2, xrT);
  t_gemm<<<dim3(16, 2, 8), 256, 0, stream>>>(wtb, xrT, bt, tbf, bnsum, bnss);
  final_kernel<<<dim3(4096), 256, 0, stream>>>(x, tbf, bnsum, bnss, gamma, beta, out);
}